// Round 6
// baseline (186.070 us; speedup 1.0000x reference)
//
#include <hip/hip_runtime.h>
#include <stdint.h>

#define HWPOS 1024
#define CCH   256
#define RROWS 128   // 2B
#define EPSF  1.1920928955078125e-07f

typedef __attribute__((ext_vector_type(8))) short   short8;
typedef __attribute__((ext_vector_type(4))) float   float4v;

__device__ __forceinline__ unsigned short f2bf(float f) {
  uint32_t x = __float_as_uint(f);
  x += 0x7FFFu + ((x >> 16) & 1u);          // RNE bf16
  return (unsigned short)(x >> 16);
}

// ws layout (16B-chunk units): addr16(hw,q,r,s8) = hw*4096 + q*1024 + r*8 + s8
//   q = c-quarter (64 channels = 8 chunks), r = row 0..127, s8 = swizzled
//   slot-in-quarter 0..7 (data chunk c8 stored at low3(c8)^(r&7) in its group).
//   Each (hw,q) quarter is 16 KB contiguous -> single DMA unit for k_gram.

// ---------------------------------------------------------------------------
// Kernel 1 (v4): transpose [B,C,H,W] f32 -> ws bf16 (layout above).
// Block = rows {rr, rr+64} x 32 hw x 256 c. Lane: 16 float4 loads in flight
// (8 per source row; rows come from different input tensors -> independent),
// 2x the MLP of v3. Per wave-instruction: 8 FULL 128B granules.
// ---------------------------------------------------------------------------
__global__ __launch_bounds__(256) void k_transpose(const float* __restrict__ inp,
                                                   const float* __restrict__ tgt,
                                                   unsigned short* __restrict__ wsF) {
  const int t   = threadIdx.x;
  const int j   = t & 7;          // chunk-within-group
  const int h4  = (t >> 3) & 7;   // hw quad index (4 hw each)
  const int g   = t >> 6;         // wave id = chunk group (0..3)
  const int rr  = blockIdx.y;     // 0..63: handles rows rr (inp) and rr+64 (tgt)
  const int hw0 = blockIdx.x * 32;
  const int m   = rr & 7;         // (rr+64)&7 == rr&7
  const int slot = g * 8 + j;           // destination 16B chunk (0..31)
  const int c8   = g * 8 + (j ^ m);     // source data chunk
  const int q4   = slot >> 3;           // quarter
  const int s8   = slot & 7;            // slot within quarter
  const size_t coff = (size_t)c8 * 8 * HWPOS + hw0 + h4 * 4;
  const float* p0 = inp + (size_t)rr * CCH * HWPOS + coff;
  const float* p1 = tgt + (size_t)rr * CCH * HWPOS + coff;
  float4 v0[8], v1[8];
#pragma unroll
  for (int e = 0; e < 8; ++e) v0[e] = *(const float4*)(p0 + (size_t)e * HWPOS);
#pragma unroll
  for (int e = 0; e < 8; ++e) v1[e] = *(const float4*)(p1 + (size_t)e * HWPOS);
#pragma unroll
  for (int rsel = 0; rsel < 2; ++rsel) {
    const int r = rsel ? (rr + 64) : rr;
    float4* v = rsel ? v1 : v0;
#pragma unroll
    for (int qq = 0; qq < 4; ++qq) {
      float s0 = (qq == 0) ? v[0].x : (qq == 1) ? v[0].y : (qq == 2) ? v[0].z : v[0].w;
      float s1 = (qq == 0) ? v[1].x : (qq == 1) ? v[1].y : (qq == 2) ? v[1].z : v[1].w;
      float s2 = (qq == 0) ? v[2].x : (qq == 1) ? v[2].y : (qq == 2) ? v[2].z : v[2].w;
      float s3 = (qq == 0) ? v[3].x : (qq == 1) ? v[3].y : (qq == 2) ? v[3].z : v[3].w;
      float s4 = (qq == 0) ? v[4].x : (qq == 1) ? v[4].y : (qq == 2) ? v[4].z : v[4].w;
      float s5 = (qq == 0) ? v[5].x : (qq == 1) ? v[5].y : (qq == 2) ? v[5].z : v[5].w;
      float s6 = (qq == 0) ? v[6].x : (qq == 1) ? v[6].y : (qq == 2) ? v[6].z : v[6].w;
      float s7 = (qq == 0) ? v[7].x : (qq == 1) ? v[7].y : (qq == 2) ? v[7].z : v[7].w;
      uint4 o;
      o.x = f2bf(s0) | ((uint32_t)f2bf(s1) << 16);
      o.y = f2bf(s2) | ((uint32_t)f2bf(s3) << 16);
      o.z = f2bf(s4) | ((uint32_t)f2bf(s5) << 16);
      o.w = f2bf(s6) | ((uint32_t)f2bf(s7) << 16);
      const size_t a16 = (size_t)(hw0 + h4 * 4 + qq) * 4096 + (size_t)q4 * 1024 + r * 8 + s8;
      *(uint4*)(wsF + a16 * 8) = o;
    }
  }
}

// ---------------------------------------------------------------------------
// Kernel 2 (v4): one block per hw. Quarter-pipelined staging: 2 x 16KB LDS
// buffers; issue DMA for quarter q+1, compute quarter q, THEN barrier -- the
// compiler's vmcnt(0)-before-s_barrier lands after compute, so the DMA is
// hidden (true intra-block overlap with plain __syncthreads).
// 8 waves; wave w owns row-tile w x 8 col-tiles. No dynamic register indexing.
// ---------------------------------------------------------------------------
__global__ __launch_bounds__(512, 4) void k_gram(const unsigned short* __restrict__ wsF,
                                                 float* __restrict__ out) {
  __shared__ unsigned short Fs[2][8192];   // 2 x 16 KB quarter buffers
  __shared__ float sInv[RROWS];
  __shared__ float wred[8];
  const int t  = threadIdx.x;
  const int hw = blockIdx.x;
  const int lane = t & 63;
  const int w    = t >> 6;        // wave id 0..7 = row-tile
  const int lid  = lane & 15;
  const int quad = lane >> 4;
  const int lm   = lid & 7;       // r&7 for every row this lane touches
  float4v acc[8];
#pragma unroll
  for (int ni = 0; ni < 8; ++ni) acc[ni] = (float4v){0.f, 0.f, 0.f, 0.f};
  const unsigned short* gsrc = wsF + (size_t)hw * 65536;  // shorts per hw
  // stage quarter 0 into buffer 0
#pragma unroll
  for (int it = 0; it < 2; ++it) {
    const size_t ch = (size_t)it * 512 + t;
    __builtin_amdgcn_global_load_lds(
        (const __attribute__((address_space(1))) unsigned int*)(gsrc + ch * 8),
        (__attribute__((address_space(3))) unsigned int*)(&Fs[0][0] + ch * 8),
        16, 0, 0);
  }
  __syncthreads();
#pragma unroll
  for (int q = 0; q < 4; ++q) {
    if (q < 3) {  // issue DMA for next quarter into other buffer (no wait)
#pragma unroll
      for (int it = 0; it < 2; ++it) {
        const size_t ch = (size_t)it * 512 + t;
        __builtin_amdgcn_global_load_lds(
            (const __attribute__((address_space(1))) unsigned int*)(gsrc + (size_t)(q + 1) * 16384 + ch * 8),
            (__attribute__((address_space(3))) unsigned int*)(&Fs[(q + 1) & 1][0] + ch * 8),
            16, 0, 0);
      }
    }
    const unsigned short* B = &Fs[q & 1][0];
#pragma unroll
    for (int ks2 = 0; ks2 < 2; ++ks2) {
      const int off = (((ks2 * 4 + quad) ^ lm) << 3);   // swizzled slot offset
      short8 a = *(const short8*)&B[((w << 4) | lid) * 64 + off];
#pragma unroll
      for (int ni = 0; ni < 8; ++ni) {
        short8 b = *(const short8*)&B[((ni << 4) | lid) * 64 + off];
        acc[ni] = __builtin_amdgcn_mfma_f32_16x16x32_bf16(a, b, acc[ni], 0, 0, 0);
      }
    }
    __syncthreads();   // drains next-quarter DMA (had full compute to finish)
  }
  // diagonal extract (no dynamic indexing): tile w (uniform), elem lid&3
  {
    float diagv = 0.f;
#pragma unroll
    for (int ni = 0; ni < 8; ++ni) {
      if (ni == w) {
#pragma unroll
        for (int e = 0; e < 4; ++e)
          if (e == (lid & 3)) diagv = acc[ni][e];
      }
    }
    if ((lid >> 2) == quad) {
      sInv[(w << 4) | lid] = 1.0f / fmaxf(sqrtf(diagv), EPSF);
    }
  }
  __syncthreads();
  float invj[8];
#pragma unroll
  for (int ni = 0; ni < 8; ++ni) invj[ni] = sInv[(ni << 4) | lid];
  const int tj = (w + 4) & 7;     // partner col-tile (wave-uniform)
  float lacc = 0.f;
#pragma unroll
  for (int reg = 0; reg < 4; ++reg) {
    const int rloc = quad * 4 + reg;           // local row in tile
    const int rg   = (w << 4) | rloc;          // global row 0..127
    const float invi = sInv[rg];
    float v[8];
#pragma unroll
    for (int ni = 0; ni < 8; ++ni) v[ni] = 2.0f * acc[ni][reg] * invi * invj[ni];
#pragma unroll
    for (int ni = 0; ni < 8; ++ni)
      if (ni == w && lid == rloc) v[ni] = -3.0e38f;   // mask diagonal
    float mx = v[0];
#pragma unroll
    for (int ni = 1; ni < 8; ++ni) mx = fmaxf(mx, v[ni]);
#pragma unroll
    for (int s = 1; s < 16; s <<= 1) mx = fmaxf(mx, __shfl_xor(mx, s, 16));
    float sm = 0.f;
#pragma unroll
    for (int ni = 0; ni < 8; ++ni) sm += __expf(v[ni] - mx);
#pragma unroll
    for (int s = 1; s < 16; s <<= 1) sm += __shfl_xor(sm, s, 16);
    const float lse = mx + __logf(sm);
    float cand = 0.f;
#pragma unroll
    for (int ni = 0; ni < 8; ++ni)
      if (ni == tj) cand = v[ni];                // positive-pair tile (uniform)
    const float vp = __shfl(cand, rloc, 16);
    lacc += vp - lse;                            // x16 lanes per row
  }
#pragma unroll
  for (int s = 1; s < 64; s <<= 1) lacc += __shfl_xor(lacc, s, 64);
  if (lane == 0) wred[w] = lacc;
  __syncthreads();
  if (t == 0) {
    float tot = 0.f;
#pragma unroll
    for (int i = 0; i < 8; ++i) tot += wred[i];
    // tot = 16 * sum_rows(pos) for this hw; loss = -sum/(HW*2B) with x16 dup
    atomicAdd(out, -tot * (1.0f / 2097152.0f));
  }
}

__global__ void k_zero(float* __restrict__ out) { out[0] = 0.0f; }

extern "C" void kernel_launch(void* const* d_in, const int* in_sizes, int n_in,
                              void* d_out, int out_size, void* d_ws, size_t ws_size,
                              hipStream_t stream) {
  const float* inp = (const float*)d_in[0];
  const float* tgt = (const float*)d_in[1];
  unsigned short* wsF = (unsigned short*)d_ws;
  k_zero<<<1, 1, 0, stream>>>((float*)d_out);
  k_transpose<<<dim3(32, 64), 256, 0, stream>>>(inp, tgt, wsF);
  k_gram<<<dim3(HWPOS), 512, 0, stream>>>(wsF, (float*)d_out);
}